// Round 1
// baseline (63.712 us; speedup 1.0000x reference)
//
#include <hip/hip_runtime.h>
#include <hip/hip_bf16.h>

// Capsule routing-by-agreement: capsule_outputs [B=16384, N=64, D=64] fp32.
// 3 iterations of { c = softmax(b over N); s = sum_n c[n]*X[n,:]; v = squash(s);
//                   b += X @ v }  -> output v [B, 64] fp32.
// One block per batch element; tile cached in LDS; single HBM pass.

#define N_CAPS 64
#define D_DIM  64
#define LDS_STRIDE 65   // +1 pad: row-per-lane reads conflict-free

__global__ __launch_bounds__(256)
void routing_kernel(const float* __restrict__ X, float* __restrict__ out) {
    __shared__ float xs[N_CAPS * LDS_STRIDE];  // padded [64][65]
    __shared__ float cb[N_CAPS];               // softmax coefficients c[n]
    __shared__ float vv[D_DIM];                // v[d]
    __shared__ float part[4][64];              // cross-wave partials
    __shared__ float blog[N_CAPS];             // routing logits b[n]

    const int tid  = threadIdx.x;
    const int lane = tid & 63;     // d for s-phase, n for agreement-phase
    const int q    = tid >> 6;     // wave id 0..3 -> quarter of reduction axis
    const float* Xb = X + (size_t)blockIdx.x * (N_CAPS * D_DIM);

    // ---- stage tile: 4096 floats, 4x float4 per thread, coalesced ----
    #pragma unroll
    for (int i = 0; i < 4; ++i) {
        int f = (tid + i * 256) * 4;            // flat element index
        float4 val = *reinterpret_cast<const float4*>(Xb + f);
        int r = f >> 6, c = f & 63;
        float* dst = &xs[r * LDS_STRIDE + c];
        dst[0] = val.x; dst[1] = val.y; dst[2] = val.z; dst[3] = val.w;
    }
    if (tid < N_CAPS) blog[tid] = 0.0f;
    __syncthreads();

    for (int it = 0; it < 3; ++it) {
        // ---- softmax over b[0..63] : wave 0, butterfly reduce ----
        if (tid < 64) {
            float bl = blog[tid];
            float m = bl;
            #pragma unroll
            for (int off = 32; off; off >>= 1) m = fmaxf(m, __shfl_xor(m, off));
            float e = __expf(bl - m);
            float ssum = e;
            #pragma unroll
            for (int off = 32; off; off >>= 1) ssum += __shfl_xor(ssum, off);
            cb[tid] = e / ssum;
        }
        __syncthreads();

        // ---- s[d] = sum_n c[n] * X[n][d]; wave q handles n in [16q,16q+16) ----
        {
            float p = 0.0f;
            #pragma unroll
            for (int k = 0; k < 16; ++k) {
                int n = q * 16 + k;
                p += cb[n] * xs[n * LDS_STRIDE + lane];  // lane=d: conflict-free
            }
            part[q][lane] = p;
        }
        __syncthreads();

        // ---- squash: wave 0 ----
        if (tid < 64) {
            float s = part[0][tid] + part[1][tid] + part[2][tid] + part[3][tid];
            float n2 = s * s;
            #pragma unroll
            for (int off = 32; off; off >>= 1) n2 += __shfl_xor(n2, off);
            float norm = sqrtf(n2);
            float scale = n2 / (1.0f + n2) / (norm + 1e-8f);
            vv[tid] = scale * s;
        }
        __syncthreads();

        if (it < 2) {
            // ---- agreement: b[n] += sum_d X[n][d]*v[d]; wave q handles d-quarter ----
            float a = 0.0f;
            #pragma unroll
            for (int k = 0; k < 16; ++k) {
                int dd = q * 16 + k;
                a += xs[lane * LDS_STRIDE + dd] * vv[dd];  // pad -> conflict-free
            }
            part[q][lane] = a;
            __syncthreads();
            if (tid < 64)
                blog[tid] += part[0][tid] + part[1][tid] + part[2][tid] + part[3][tid];
            __syncthreads();
        }
    }

    if (tid < 64) out[(size_t)blockIdx.x * D_DIM + tid] = vv[tid];
}

extern "C" void kernel_launch(void* const* d_in, const int* in_sizes, int n_in,
                              void* d_out, int out_size, void* d_ws, size_t ws_size,
                              hipStream_t stream) {
    const float* X = (const float*)d_in[0];
    float* out = (float*)d_out;
    const int B = in_sizes[0] / (N_CAPS * D_DIM);   // 16384
    routing_kernel<<<B, 256, 0, stream>>>(X, out);
}

// Round 2
// 48.258 us; speedup vs baseline: 1.3202x; 1.3202x over previous
//
#include <hip/hip_runtime.h>
#include <hip/hip_bf16.h>

// Capsule routing-by-agreement: X [B, N=64, D=64] fp32 -> v [B, 64] fp32.
// One WAVE per batch element, entire 16KB tile register-resident:
//   lane l (h=l>>4, g=l&15) holds X[4i+h][4g..4g+3], i=0..15  (16 x float4).
// All reductions are shfl_xor butterflies; zero LDS, zero barriers.

__global__ __launch_bounds__(256)
void routing_kernel(const float* __restrict__ X, float* __restrict__ out, int B) {
    const int w = (blockIdx.x << 2) + (threadIdx.x >> 6);  // batch element (wave-uniform)
    if (w >= B) return;
    const int l = threadIdx.x & 63;
    const int g = l & 15;

    const float* Xb = X + (size_t)w * 4096;

    // ---- load: instr i reads a contiguous 1KB row-pair slice (coalesced) ----
    float4 data[16];
    #pragma unroll
    for (int i = 0; i < 16; ++i)
        data[i] = *reinterpret_cast<const float4*>(Xb + i * 256 + 4 * l);

    float blog[16];   // routing logits for rows 4i+h (per-lane slice)
    #pragma unroll
    for (int i = 0; i < 16; ++i) blog[i] = 0.0f;

    float c[16];
    float4 v4 = make_float4(0.f, 0.f, 0.f, 0.f);

    for (int it = 0; it < 3; ++it) {
        // ---- softmax over the 64 rows (c uniform on iter 0) ----
        float4 s4;
        if (it == 0) {
            s4 = make_float4(0.f, 0.f, 0.f, 0.f);
            #pragma unroll
            for (int i = 0; i < 16; ++i) {
                s4.x += data[i].x; s4.y += data[i].y;
                s4.z += data[i].z; s4.w += data[i].w;
            }
            s4.x *= 0.015625f; s4.y *= 0.015625f; s4.z *= 0.015625f; s4.w *= 0.015625f;
        } else {
            float m = blog[0];
            #pragma unroll
            for (int i = 1; i < 16; ++i) m = fmaxf(m, blog[i]);
            m = fmaxf(m, __shfl_xor(m, 16));   // reduce over h
            m = fmaxf(m, __shfl_xor(m, 32));
            float sum = 0.0f;
            #pragma unroll
            for (int i = 0; i < 16; ++i) { c[i] = __expf(blog[i] - m); sum += c[i]; }
            sum += __shfl_xor(sum, 16);
            sum += __shfl_xor(sum, 32);
            const float r = 1.0f / sum;
            #pragma unroll
            for (int i = 0; i < 16; ++i) c[i] *= r;

            // ---- s[4g+e] = sum_n c[n] * X[n][4g+e] : local rows, then h-butterfly ----
            s4 = make_float4(0.f, 0.f, 0.f, 0.f);
            #pragma unroll
            for (int i = 0; i < 16; ++i) {
                s4.x = fmaf(c[i], data[i].x, s4.x);
                s4.y = fmaf(c[i], data[i].y, s4.y);
                s4.z = fmaf(c[i], data[i].z, s4.z);
                s4.w = fmaf(c[i], data[i].w, s4.w);
            }
        }
        #pragma unroll
        for (int off = 16; off <= 32; off <<= 1) {
            s4.x += __shfl_xor(s4.x, off);
            s4.y += __shfl_xor(s4.y, off);
            s4.z += __shfl_xor(s4.z, off);
            s4.w += __shfl_xor(s4.w, off);
        }

        // ---- squash: n2 = sum_d s[d]^2 via g-butterfly ----
        float n2 = s4.x * s4.x + s4.y * s4.y + s4.z * s4.z + s4.w * s4.w;
        #pragma unroll
        for (int off = 1; off <= 8; off <<= 1) n2 += __shfl_xor(n2, off);
        const float norm = sqrtf(n2);
        const float scale = n2 / (1.0f + n2) / (norm + 1e-8f);
        v4.x = scale * s4.x; v4.y = scale * s4.y;
        v4.z = scale * s4.z; v4.w = scale * s4.w;

        if (it < 2) {
            // ---- agreement: b[4i+h] += X[row] . v  (v lane-local: same cols) ----
            #pragma unroll
            for (int i = 0; i < 16; ++i) {
                float a = data[i].x * v4.x + data[i].y * v4.y
                        + data[i].z * v4.z + data[i].w * v4.w;
                #pragma unroll
                for (int off = 1; off <= 8; off <<= 1) a += __shfl_xor(a, off);
                blog[i] += a;   // full row-dot, consistent within h-group
            }
        }
    }

    // lanes h==0 (l<16) write v for cols 4g..4g+3 (256B coalesced per wave)
    if (l < 16)
        *reinterpret_cast<float4*>(out + (size_t)w * 64 + 4 * g) = v4;
}

extern "C" void kernel_launch(void* const* d_in, const int* in_sizes, int n_in,
                              void* d_out, int out_size, void* d_ws, size_t ws_size,
                              hipStream_t stream) {
    const float* X = (const float*)d_in[0];
    float* out = (float*)d_out;
    const int B = in_sizes[0] / 4096;        // 16384
    const int blocks = (B + 3) / 4;          // 4 independent waves per block
    routing_kernel<<<blocks, 256, 0, stream>>>(X, out, B);
}